// Round 1
// baseline (1328.277 us; speedup 1.0000x reference)
//
#include <hip/hip_runtime.h>
#include <hip/hip_bf16.h>

typedef float  f32x4  __attribute__((ext_vector_type(4)));
typedef __bf16 bf16x8 __attribute__((ext_vector_type(8)));
typedef short  s16x8  __attribute__((ext_vector_type(8)));
typedef short  s16x4  __attribute__((ext_vector_type(4)));

// fp32 -> bf16 round-to-nearest-even (raw bits in short)
__device__ __forceinline__ short f2b(float f) {
  unsigned u = __builtin_bit_cast(unsigned, f);
  u = (u + 0x7fffu + ((u >> 16) & 1u)) >> 16;
  return (short)u;
}
// bf16 bits -> fp32 (exact)
__device__ __forceinline__ float b2f(short s) {
  unsigned u = ((unsigned)(unsigned short)s) << 16;
  return __builtin_bit_cast(float, u);
}
// 4 fp32 -> 4 bf16 (packed cvt)
__device__ __forceinline__ s16x4 pack4(f32x4 a) {
  union { s16x4 v; __hip_bfloat162 h[2]; } u;
  u.h[0] = __float22bfloat162_rn(make_float2(a[0], a[1]));
  u.h[1] = __float22bfloat162_rn(make_float2(a[2], a[3]));
  return u.v;
}

// W [2][256 c][256 d] fp32  ->  Wt [2][256 d][256 c] bf16 (B-operand friendly)
__global__ void prep_wt(const float* __restrict__ W, short* __restrict__ Wt) {
  int q = blockIdx.x * blockDim.x + threadIdx.x;   // 0..32767, each handles 4 elems
  int mat = q >> 14;
  int rem = q & 16383;
  int d   = rem >> 6;
  int c4  = (rem & 63) << 2;
  const float* src = W + mat * 65536;
  s16x4 o;
  #pragma unroll
  for (int i = 0; i < 4; ++i) o[i] = f2b(src[(c4 + i) * 256 + d]);
  *(s16x4*)&Wt[q << 2] = o;   // flat = mat*65536 + d*256 + c4
}

// R5 = R4 with the ct col-split merged into one 512-thread / 8-wave block:
//  - Each block computes the full 68x256 output tile; x tile staged to LDS ONCE
//    (halves x HBM fetch: the old (bt,ct=0/1) pair landed on different XCDs and
//    each fetched the tile from HBM).
//  - Per-wave shape unchanged: wave wv owns cols wv*32..wv*32+31, acc[5][4] =
//    80 AGPR, so the 128-VGPR cap of __launch_bounds__(512,4) (2 blocks/CU =
//    16 waves/CU, double R4's 8) still closes.
//  - LDS: xs[68][264] (35.9KB) union'd under sbuf[68][264]+gbuf[68][264]
//    (71.8KB total) + aoff/diag -> 73.0KB/block -> exactly 2 blocks/CU.
//  - M multiply moved from phase 1 to phase 2: 17 L1-resident M loads/thread
//    (reused across both batch groups) instead of 40.
__global__ __launch_bounds__(512, 4)
void fused_mgc(const float* __restrict__ x, const short* __restrict__ Wt,
               const float* __restrict__ M, const float* __restrict__ adj,
               const float* __restrict__ adj2, const float* __restrict__ bias,
               float* __restrict__ out) {
  __shared__ short smem[35904];   // xs[68][264] | union | sbuf[68][264]+gbuf[68][264]
  __shared__ float aoff[289];     // symmetrized A, diagonal zeroed
  __shared__ float diagl[17];     // diag of A

  const int tid  = threadIdx.x;
  const int lane = tid & 63;
  const int wv   = tid >> 6;      // 0..7
  const int m16  = lane & 15;
  const int qd   = lane >> 4;

  const int bt = blockIdx.x;      // batch tile: rows bt*68 .. +68 (68 = 4*17)

  for (int idx = tid; idx < 289; idx += 512) {
    int i = idx / 17, j = idx - i * 17;
    float v = 0.5f * ((adj[i*17+j] + adj2[i*17+j]) + (adj[j*17+i] + adj2[j*17+i]));
    aoff[idx] = (i == j) ? 0.0f : v;
    if (i == j) diagl[i] = adj[i*17+i] + adj2[i*17+i];
  }

  // ---- stage x tile: 68 rows x 256 k, fp32 -> bf16 LDS (stride 264 shorts) ----
  {
    const float* xbase = x + (size_t)bt * 68 * 256;
    const int c4 = (tid & 63) << 2;   // col quad: 64 quads = 256 cols = 1 row/wave-op
    const int r0 = tid >> 6;          // 0..7
    #pragma unroll
    for (int it = 0; it < 9; ++it) {
      int row = r0 + it * 8;
      if (row < 68) {
        f32x4 v = *(const f32x4*)&xbase[row * 256 + c4];
        *(s16x4*)&smem[row * 264 + c4] = pack4(v);
      }
    }
  }

  f32x4 acc[5][4];  // [rowfrag][mat*2+colfrag]
  #pragma unroll
  for (int a = 0; a < 5; ++a)
    #pragma unroll
    for (int b = 0; b < 4; ++b) acc[a][b] = (f32x4)0.0f;

  const short* wbase = Wt + (wv * 32 + m16) * 256;  // + mat*65536 + cf*4096

  __syncthreads();   // xs (and aoff/diagl) ready

  // A-row indices (clamped: rows 68..79 read row 67; their C-rows are never stored)
  int arow[5];
  #pragma unroll
  for (int rf = 0; rf < 5; ++rf) {
    int r = rf * 16 + m16;
    arow[rf] = (r < 68 ? r : 67) * 264;
  }

  #pragma unroll
  for (int ks = 0; ks < 8; ++ks) {
    const int kq = ks * 32 + qd * 8;
    bf16x8 bfr[4];
    #pragma unroll
    for (int mc = 0; mc < 4; ++mc) {
      int mat = mc >> 1, cf = mc & 1;
      s16x8 t = *(const s16x8*)&wbase[mat * 65536 + cf * 4096 + kq];
      bfr[mc] = __builtin_bit_cast(bf16x8, t);
    }
    #pragma unroll
    for (int rf = 0; rf < 5; ++rf) {
      s16x8 t = *(const s16x8*)&smem[arow[rf] + kq];
      bf16x8 af = __builtin_bit_cast(bf16x8, t);
      #pragma unroll
      for (int mc = 0; mc < 4; ++mc)
        acc[rf][mc] = __builtin_amdgcn_mfma_f32_16x16x32_bf16(af, bfr[mc], acc[rf][mc], 0, 0, 0);
    }
  }

  __syncthreads();   // all waves done reading xs; reuse smem for epilogue
  short* sbuf = smem;           // [68][264] bf16: h0 (raw)
  short* gbuf = smem + 17952;   // [68][264] bf16: h1 (raw)

  // phase 1: registers (C-layout: col=lane&15, row=(lane>>4)*4+reg) -> LDS as bf16
  #pragma unroll
  for (int rf = 0; rf < 5; ++rf) {
    #pragma unroll
    for (int cf = 0; cf < 2; ++cf) {
      int c = wv * 32 + cf * 16 + m16;
      #pragma unroll
      for (int reg = 0; reg < 4; ++reg) {
        int r = rf * 16 + qd * 4 + reg;
        if (r < 68) {
          sbuf[r * 264 + c] = f2b(acc[rf][cf][reg]);
          gbuf[r * 264 + c] = f2b(acc[rf][2 + cf][reg]);
        }
      }
    }
  }
  __syncthreads();
  // phase 2: mixing. i,j uniform across threads -> aoff/diagl reads are broadcasts.
  const int d7   = tid & 255;
  const int half = tid >> 8;
  const float bi = bias[d7];
  float mv[17], dmv[17];
  #pragma unroll
  for (int j = 0; j < 17; ++j) {
    mv[j]  = M[j * 256 + d7];
    dmv[j] = diagl[j] * mv[j];
  }
  #pragma unroll
  for (int gg = 0; gg < 2; ++gg) {
    int g = half * 2 + gg;           // batch-group within tile (0..3)
    int rbase = g * 17;
    float gr[17];
    #pragma unroll
    for (int j = 0; j < 17; ++j) gr[j] = mv[j] * b2f(gbuf[(rbase + j) * 264 + d7]);
    #pragma unroll
    for (int i = 0; i < 17; ++i) {
      float s = dmv[i] * b2f(sbuf[(rbase + i) * 264 + d7]) + bi;
      #pragma unroll
      for (int j = 0; j < 17; ++j) s += aoff[i * 17 + j] * gr[j];
      out[((bt * 4 + g) * 17 + i) * 256 + d7] = s;
    }
  }
}

extern "C" void kernel_launch(void* const* d_in, const int* in_sizes, int n_in,
                              void* d_out, int out_size, void* d_ws, size_t ws_size,
                              hipStream_t stream) {
  const float* x    = (const float*)d_in[0];
  const float* W    = (const float*)d_in[1];
  const float* M    = (const float*)d_in[2];
  const float* adj  = (const float*)d_in[3];
  const float* adj2 = (const float*)d_in[4];
  const float* bias = (const float*)d_in[5];
  float* out = (float*)d_out;
  short* Wt  = (short*)d_ws;   // 262144 B scratch for transposed bf16 weights

  prep_wt<<<128, 256, 0, stream>>>(W, Wt);
  fused_mgc<<<2048, 512, 0, stream>>>(x, Wt, M, adj, adj2, bias, out);
}

// Round 2
// 920.950 us; speedup vs baseline: 1.4423x; 1.4423x over previous
//
#include <hip/hip_runtime.h>
#include <hip/hip_bf16.h>

typedef float  f32x4  __attribute__((ext_vector_type(4)));
typedef __bf16 bf16x8 __attribute__((ext_vector_type(8)));
typedef short  s16x8  __attribute__((ext_vector_type(8)));
typedef short  s16x4  __attribute__((ext_vector_type(4)));

// fp32 -> bf16 round-to-nearest-even (raw bits in short)
__device__ __forceinline__ short f2b(float f) {
  unsigned u = __builtin_bit_cast(unsigned, f);
  u = (u + 0x7fffu + ((u >> 16) & 1u)) >> 16;
  return (short)u;
}
// bf16 bits -> fp32 (exact)
__device__ __forceinline__ float b2f(short s) {
  unsigned u = ((unsigned)(unsigned short)s) << 16;
  return __builtin_bit_cast(float, u);
}
// 4 fp32 -> 4 bf16 (packed cvt)
__device__ __forceinline__ s16x4 pack4(f32x4 a) {
  union { s16x4 v; __hip_bfloat162 h[2]; } u;
  u.h[0] = __float22bfloat162_rn(make_float2(a[0], a[1]));
  u.h[1] = __float22bfloat162_rn(make_float2(a[2], a[3]));
  return u.v;
}

// W [2][256 c][256 d] fp32  ->  Wt [2][256 d][256 c] bf16 (B-operand friendly)
__global__ void prep_wt(const float* __restrict__ W, short* __restrict__ Wt) {
  int q = blockIdx.x * blockDim.x + threadIdx.x;   // 0..32767, each handles 4 elems
  int mat = q >> 14;
  int rem = q & 16383;
  int d   = rem >> 6;
  int c4  = (rem & 63) << 2;
  const float* src = W + mat * 65536;
  s16x4 o;
  #pragma unroll
  for (int i = 0; i < 4; ++i) o[i] = f2b(src[(c4 + i) * 256 + d]);
  *(s16x4*)&Wt[q << 2] = o;   // flat = mat*65536 + d*256 + c4
}

// R6 = R5 with the launch bound corrected.
//  MEASURED (R5): __launch_bounds__(512,4) produced a 64-VGPR cap -> the 2nd
//  arg is interpreted CUDA-style as MIN BLOCKS/CU on this toolchain
//  (4 blocks x 8 waves = 32 waves/CU -> 8 waves/SIMD -> 512/8 = 64 regs),
//  NOT waves/EU. Result was massive scratch spill (WRITE_SIZE 2.1 GB).
//  (512,2) -> 2 blocks/CU x 8 waves = 16 waves/CU -> cap 512/4 = 128 VGPR,
//  which this per-wave code fits exactly (R4 compiled to 128).
//  - Each block computes the full 68x256 output tile; x staged to LDS once.
//  - LDS: xs[68][264] union'd under sbuf+gbuf -> 73.0KB/block -> 2 blocks/CU.
__global__ __launch_bounds__(512, 2)
void fused_mgc(const float* __restrict__ x, const short* __restrict__ Wt,
               const float* __restrict__ M, const float* __restrict__ adj,
               const float* __restrict__ adj2, const float* __restrict__ bias,
               float* __restrict__ out) {
  __shared__ short smem[35904];   // xs[68][264] | union | sbuf[68][264]+gbuf[68][264]
  __shared__ float aoff[289];     // symmetrized A, diagonal zeroed
  __shared__ float diagl[17];     // diag of A

  const int tid  = threadIdx.x;
  const int lane = tid & 63;
  const int wv   = tid >> 6;      // 0..7
  const int m16  = lane & 15;
  const int qd   = lane >> 4;

  const int bt = blockIdx.x;      // batch tile: rows bt*68 .. +68 (68 = 4*17)

  for (int idx = tid; idx < 289; idx += 512) {
    int i = idx / 17, j = idx - i * 17;
    float v = 0.5f * ((adj[i*17+j] + adj2[i*17+j]) + (adj[j*17+i] + adj2[j*17+i]));
    aoff[idx] = (i == j) ? 0.0f : v;
    if (i == j) diagl[i] = adj[i*17+i] + adj2[i*17+i];
  }

  // ---- stage x tile: 68 rows x 256 k, fp32 -> bf16 LDS (stride 264 shorts) ----
  {
    const float* xbase = x + (size_t)bt * 68 * 256;
    const int c4 = (tid & 63) << 2;   // col quad: 64 quads = 256 cols = 1 row/wave-op
    const int r0 = tid >> 6;          // 0..7
    #pragma unroll
    for (int it = 0; it < 9; ++it) {
      int row = r0 + it * 8;
      if (row < 68) {
        f32x4 v = *(const f32x4*)&xbase[row * 256 + c4];
        *(s16x4*)&smem[row * 264 + c4] = pack4(v);
      }
    }
  }

  f32x4 acc[5][4];  // [rowfrag][mat*2+colfrag]
  #pragma unroll
  for (int a = 0; a < 5; ++a)
    #pragma unroll
    for (int b = 0; b < 4; ++b) acc[a][b] = (f32x4)0.0f;

  const short* wbase = Wt + (wv * 32 + m16) * 256;  // + mat*65536 + cf*4096

  __syncthreads();   // xs (and aoff/diagl) ready

  // A-row indices (clamped: rows 68..79 read row 67; their C-rows are never stored)
  int arow[5];
  #pragma unroll
  for (int rf = 0; rf < 5; ++rf) {
    int r = rf * 16 + m16;
    arow[rf] = (r < 68 ? r : 67) * 264;
  }

  #pragma unroll
  for (int ks = 0; ks < 8; ++ks) {
    const int kq = ks * 32 + qd * 8;
    bf16x8 bfr[4];
    #pragma unroll
    for (int mc = 0; mc < 4; ++mc) {
      int mat = mc >> 1, cf = mc & 1;
      s16x8 t = *(const s16x8*)&wbase[mat * 65536 + cf * 4096 + kq];
      bfr[mc] = __builtin_bit_cast(bf16x8, t);
    }
    #pragma unroll
    for (int rf = 0; rf < 5; ++rf) {
      s16x8 t = *(const s16x8*)&smem[arow[rf] + kq];
      bf16x8 af = __builtin_bit_cast(bf16x8, t);
      #pragma unroll
      for (int mc = 0; mc < 4; ++mc)
        acc[rf][mc] = __builtin_amdgcn_mfma_f32_16x16x32_bf16(af, bfr[mc], acc[rf][mc], 0, 0, 0);
    }
  }

  __syncthreads();   // all waves done reading xs; reuse smem for epilogue
  short* sbuf = smem;           // [68][264] bf16: h0 (raw)
  short* gbuf = smem + 17952;   // [68][264] bf16: h1 (raw)

  // phase 1: registers (C-layout: col=lane&15, row=(lane>>4)*4+reg) -> LDS as bf16
  #pragma unroll
  for (int rf = 0; rf < 5; ++rf) {
    #pragma unroll
    for (int cf = 0; cf < 2; ++cf) {
      int c = wv * 32 + cf * 16 + m16;
      #pragma unroll
      for (int reg = 0; reg < 4; ++reg) {
        int r = rf * 16 + qd * 4 + reg;
        if (r < 68) {
          sbuf[r * 264 + c] = f2b(acc[rf][cf][reg]);
          gbuf[r * 264 + c] = f2b(acc[rf][2 + cf][reg]);
        }
      }
    }
  }
  __syncthreads();
  // phase 2: mixing. i,j uniform across threads -> aoff/diagl reads are broadcasts.
  const int d7   = tid & 255;
  const int half = tid >> 8;
  const float bi = bias[d7];
  float mv[17], dmv[17];
  #pragma unroll
  for (int j = 0; j < 17; ++j) {
    mv[j]  = M[j * 256 + d7];
    dmv[j] = diagl[j] * mv[j];
  }
  #pragma unroll
  for (int gg = 0; gg < 2; ++gg) {
    int g = half * 2 + gg;           // batch-group within tile (0..3)
    int rbase = g * 17;
    float gr[17];
    #pragma unroll
    for (int j = 0; j < 17; ++j) gr[j] = mv[j] * b2f(gbuf[(rbase + j) * 264 + d7]);
    #pragma unroll
    for (int i = 0; i < 17; ++i) {
      float s = dmv[i] * b2f(sbuf[(rbase + i) * 264 + d7]) + bi;
      #pragma unroll
      for (int j = 0; j < 17; ++j) s += aoff[i * 17 + j] * gr[j];
      out[((bt * 4 + g) * 17 + i) * 256 + d7] = s;
    }
  }
}

extern "C" void kernel_launch(void* const* d_in, const int* in_sizes, int n_in,
                              void* d_out, int out_size, void* d_ws, size_t ws_size,
                              hipStream_t stream) {
  const float* x    = (const float*)d_in[0];
  const float* W    = (const float*)d_in[1];
  const float* M    = (const float*)d_in[2];
  const float* adj  = (const float*)d_in[3];
  const float* adj2 = (const float*)d_in[4];
  const float* bias = (const float*)d_in[5];
  float* out = (float*)d_out;
  short* Wt  = (short*)d_ws;   // 262144 B scratch for transposed bf16 weights

  prep_wt<<<128, 256, 0, stream>>>(W, Wt);
  fused_mgc<<<2048, 512, 0, stream>>>(x, Wt, M, adj, adj2, bias, out);
}

// Round 3
// 787.758 us; speedup vs baseline: 1.6861x; 1.1691x over previous
//
#include <hip/hip_runtime.h>
#include <hip/hip_bf16.h>

typedef float  f32x4  __attribute__((ext_vector_type(4)));
typedef __bf16 bf16x8 __attribute__((ext_vector_type(8)));
typedef short  s16x8  __attribute__((ext_vector_type(8)));
typedef short  s16x4  __attribute__((ext_vector_type(4)));

// fp32 -> bf16 round-to-nearest-even (raw bits in short)
__device__ __forceinline__ short f2b(float f) {
  unsigned u = __builtin_bit_cast(unsigned, f);
  u = (u + 0x7fffu + ((u >> 16) & 1u)) >> 16;
  return (short)u;
}
// bf16 bits -> fp32 (exact)
__device__ __forceinline__ float b2f(short s) {
  unsigned u = ((unsigned)(unsigned short)s) << 16;
  return __builtin_bit_cast(float, u);
}
// 4 fp32 -> 4 bf16 (packed cvt)
__device__ __forceinline__ s16x4 pack4(f32x4 a) {
  union { s16x4 v; __hip_bfloat162 h[2]; } u;
  u.h[0] = __float22bfloat162_rn(make_float2(a[0], a[1]));
  u.h[1] = __float22bfloat162_rn(make_float2(a[2], a[3]));
  return u.v;
}

// W [2][256 c][256 d] fp32  ->  Wt [2][256 d][256 c] bf16 (B-operand friendly)
__global__ void prep_wt(const float* __restrict__ W, short* __restrict__ Wt) {
  int q = blockIdx.x * blockDim.x + threadIdx.x;   // 0..32767, each handles 4 elems
  int mat = q >> 14;
  int rem = q & 16383;
  int d   = rem >> 6;
  int c4  = (rem & 63) << 2;
  const float* src = W + mat * 65536;
  s16x4 o;
  #pragma unroll
  for (int i = 0; i < 4; ++i) o[i] = f2b(src[(c4 + i) * 256 + d]);
  *(s16x4*)&Wt[q << 2] = o;   // flat = mat*65536 + d*256 + c4
}

// R7 = R4 (the proven 292us structure, byte-identical compute) + two changes:
//  1. __launch_bounds__(256, 4): MEASURED on R5/R6 that the 2nd arg is
//     CUDA-style min BLOCKS/CU. (256,4) -> 16 waves/CU -> cap 512/4 = 128
//     VGPR = exactly what R4 already allocates voluntarily -> no new spill,
//     occupancy doubles (8 -> 16 waves/CU). LDS 37.4KB x 4 = 149.5KB <= 160 ok.
//     R5/R6's 512-thread merge is abandoned: at 512 thr the 128 cap forced
//     accumulator spill (WRITE_SIZE 1.5-2.1 GB of scratch traffic).
//  2. XCD-pair swizzle: (bt,ct=0/1) used to be consecutive blockIdx ->
//     different XCDs -> the 68KB x-tile was HBM-fetched twice. Remap so both
//     halves of a tile land on the SAME XCD consecutively; the second block
//     hits that XCD's L2. Bijective since 4096 % 8 == 0.
__global__ __launch_bounds__(256, 4)
void fused_mgc(const float* __restrict__ x, const short* __restrict__ Wt,
               const float* __restrict__ M, const float* __restrict__ adj,
               const float* __restrict__ adj2, const float* __restrict__ bias,
               float* __restrict__ out) {
  __shared__ short smem[17952];   // xs[68][264] | union | sbuf[68][132]+gbuf[68][132]
  __shared__ float aoff[289];     // symmetrized A, diagonal zeroed
  __shared__ float diagl[17];     // diag of A

  const int tid  = threadIdx.x;
  const int lane = tid & 63;
  const int wv   = tid >> 6;
  const int m16  = lane & 15;
  const int qd   = lane >> 4;

  // XCD-pair swizzle: dispatch round-robins blockIdx across 8 XCDs.
  // k = XCD, i = sequence within XCD; pair consecutive i into one tile.
  const int phys = blockIdx.x;
  const int xcd  = phys & 7;
  const int iseq = phys >> 3;          // 0..511 within this XCD
  const int bt   = xcd * 256 + (iseq >> 1);  // batch tile: rows bt*68 .. +68
  const int ct   = iseq & 1;                 // col tile (128 d); pair shares x

  for (int idx = tid; idx < 289; idx += 256) {
    int i = idx / 17, j = idx - i * 17;
    float v = 0.5f * ((adj[i*17+j] + adj2[i*17+j]) + (adj[j*17+i] + adj2[j*17+i]));
    aoff[idx] = (i == j) ? 0.0f : v;
    if (i == j) diagl[i] = adj[i*17+i] + adj2[i*17+i];
  }

  // ---- stage x tile: 68 rows x 256 k, fp32 -> bf16 LDS (stride 264 shorts) ----
  {
    const float* xbase = x + (size_t)bt * 68 * 256;
    const int c4 = (tid & 63) << 2;   // col quad: 64 quads = 256 cols = 1 row/wave-op
    const int r0 = tid >> 6;          // 0..3
    #pragma unroll
    for (int it = 0; it < 17; ++it) {
      int row = r0 + it * 4;
      f32x4 v = *(const f32x4*)&xbase[row * 256 + c4];
      *(s16x4*)&smem[row * 264 + c4] = pack4(v);
    }
  }

  f32x4 acc[5][4];  // [rowfrag][mat*2+colfrag]
  #pragma unroll
  for (int a = 0; a < 5; ++a)
    #pragma unroll
    for (int b = 0; b < 4; ++b) acc[a][b] = (f32x4)0.0f;

  const short* wbase = Wt + (ct * 128 + wv * 32 + m16) * 256;  // + mat*65536 + cf*4096

  __syncthreads();   // xs ready

  // A-row indices (clamped: rows 68..79 read row 67; their C-rows are never stored)
  int arow[5];
  #pragma unroll
  for (int rf = 0; rf < 5; ++rf) {
    int r = rf * 16 + m16;
    arow[rf] = (r < 68 ? r : 67) * 264;
  }

  #pragma unroll
  for (int ks = 0; ks < 8; ++ks) {
    const int kq = ks * 32 + qd * 8;
    bf16x8 bfr[4];
    #pragma unroll
    for (int mc = 0; mc < 4; ++mc) {
      int mat = mc >> 1, cf = mc & 1;
      s16x8 t = *(const s16x8*)&wbase[mat * 65536 + cf * 4096 + kq];
      bfr[mc] = __builtin_bit_cast(bf16x8, t);
    }
    #pragma unroll
    for (int rf = 0; rf < 5; ++rf) {
      s16x8 t = *(const s16x8*)&smem[arow[rf] + kq];
      bf16x8 af = __builtin_bit_cast(bf16x8, t);
      #pragma unroll
      for (int mc = 0; mc < 4; ++mc)
        acc[rf][mc] = __builtin_amdgcn_mfma_f32_16x16x32_bf16(af, bfr[mc], acc[rf][mc], 0, 0, 0);
    }
  }

  __syncthreads();   // all waves done reading xs; reuse smem for epilogue
  short* sbuf = smem;          // [68][132] bf16: diag_i*M*h0
  short* gbuf = smem + 8976;   // [68][132] bf16: M*h1

  // phase 1: registers (C-layout: col=lane&15, row=(lane>>4)*4+reg) -> LDS as bf16
  #pragma unroll
  for (int rf = 0; rf < 5; ++rf) {
    #pragma unroll
    for (int cf = 0; cf < 2; ++cf) {
      int c = wv * 32 + cf * 16 + m16;
      #pragma unroll
      for (int reg = 0; reg < 4; ++reg) {
        int r = rf * 16 + qd * 4 + reg;
        if (r < 68) {
          int n = r % 17;
          float mv = M[n * 256 + ct * 128 + c];
          sbuf[r * 132 + c] = f2b(diagl[n] * mv * acc[rf][cf][reg]);
          gbuf[r * 132 + c] = f2b(mv * acc[rf][2 + cf][reg]);
        }
      }
    }
  }
  __syncthreads();
  // phase 2: mixing. i,j uniform across threads -> aoff reads are broadcasts.
  const int d7   = tid & 127;
  const int half = tid >> 7;
  const float bi = bias[ct * 128 + d7];
  for (int gg = 0; gg < 2; ++gg) {
    int g = half * 2 + gg;           // batch-group within tile (0..3)
    int rbase = g * 17;
    float gr[17];
    #pragma unroll
    for (int j = 0; j < 17; ++j) gr[j] = b2f(gbuf[(rbase + j) * 132 + d7]);
    #pragma unroll
    for (int i = 0; i < 17; ++i) {
      float s = b2f(sbuf[(rbase + i) * 132 + d7]) + bi;
      #pragma unroll
      for (int j = 0; j < 17; ++j) s += aoff[i * 17 + j] * gr[j];
      out[((bt * 4 + g) * 17 + i) * 256 + ct * 128 + d7] = s;
    }
  }
}

extern "C" void kernel_launch(void* const* d_in, const int* in_sizes, int n_in,
                              void* d_out, int out_size, void* d_ws, size_t ws_size,
                              hipStream_t stream) {
  const float* x    = (const float*)d_in[0];
  const float* W    = (const float*)d_in[1];
  const float* M    = (const float*)d_in[2];
  const float* adj  = (const float*)d_in[3];
  const float* adj2 = (const float*)d_in[4];
  const float* bias = (const float*)d_in[5];
  float* out = (float*)d_out;
  short* Wt  = (short*)d_ws;   // 262144 B scratch for transposed bf16 weights

  prep_wt<<<128, 256, 0, stream>>>(W, Wt);
  fused_mgc<<<4096, 256, 0, stream>>>(x, Wt, M, adj, adj2, bias, out);
}

// Round 4
// 393.535 us; speedup vs baseline: 3.3752x; 2.0017x over previous
//
#include <hip/hip_runtime.h>
#include <hip/hip_bf16.h>

typedef float  f32x4  __attribute__((ext_vector_type(4)));
typedef __bf16 bf16x8 __attribute__((ext_vector_type(8)));
typedef short  s16x8  __attribute__((ext_vector_type(8)));
typedef short  s16x4  __attribute__((ext_vector_type(4)));

// fp32 -> bf16 round-to-nearest-even (raw bits in short)
__device__ __forceinline__ short f2b(float f) {
  unsigned u = __builtin_bit_cast(unsigned, f);
  u = (u + 0x7fffu + ((u >> 16) & 1u)) >> 16;
  return (short)u;
}
// bf16 bits -> fp32 (exact)
__device__ __forceinline__ float b2f(short s) {
  unsigned u = ((unsigned)(unsigned short)s) << 16;
  return __builtin_bit_cast(float, u);
}
// 4 fp32 -> 4 bf16 (packed cvt)
__device__ __forceinline__ s16x4 pack4(f32x4 a) {
  union { s16x4 v; __hip_bfloat162 h[2]; } u;
  u.h[0] = __float22bfloat162_rn(make_float2(a[0], a[1]));
  u.h[1] = __float22bfloat162_rn(make_float2(a[2], a[3]));
  return u.v;
}

// W [2][256 c][256 d] fp32  ->  Wt [2][256 d][256 c] bf16 (B-operand friendly)
__global__ void prep_wt(const float* __restrict__ W, short* __restrict__ Wt) {
  int q = blockIdx.x * blockDim.x + threadIdx.x;   // 0..32767, each handles 4 elems
  int mat = q >> 14;
  int rem = q & 16383;
  int d   = rem >> 6;
  int c4  = (rem & 63) << 2;
  const float* src = W + mat * 65536;
  s16x4 o;
  #pragma unroll
  for (int i = 0; i < 4; ++i) o[i] = f2b(src[(c4 + i) * 256 + d]);
  *(s16x4*)&Wt[q << 2] = o;   // flat = mat*65536 + d*256 + c4
}

// R8 = R4 compute structure + XCD-pair swizzle + UNCAPPED registers.
//  MEASURED across R4-R7: __launch_bounds__ 2nd arg caps VGPR at 256/arg2
//  regardless of block size (arg2=2 -> 128, arg2=4 -> 64). R4's cap of 128 was
//  itself a silent spill: WRITE_SIZE 401MB vs 143MB true output (+258MB scratch
//  round-trip, ~123 B/thread). Dropping the 2nd arg -> cap 512, allocator
//  takes ~150-190 regs, spill gone, and at <=170 VGPR we still get 3 waves/SIMD
//  -> 3 blocks/CU (LDS 3x37.4KB = 112KB <= 160) = 12 waves/CU > R4's 8.
//  XCD-pair swizzle (kept from R7): consecutive blockIdx round-robin across the
//  8 XCDs, so map phys -> (xcd = phys&7, iseq = phys>>3), pair iseq into one
//  (bt, ct=0/1) tile on the SAME XCD -> x tile HBM-fetched once, second read
//  hits that XCD's L2. Bijective since 4096 % 8 == 0.
__global__ __launch_bounds__(256)
void fused_mgc(const float* __restrict__ x, const short* __restrict__ Wt,
               const float* __restrict__ M, const float* __restrict__ adj,
               const float* __restrict__ adj2, const float* __restrict__ bias,
               float* __restrict__ out) {
  __shared__ short smem[17952];   // xs[68][264] | union | sbuf[68][132]+gbuf[68][132]
  __shared__ float aoff[289];     // symmetrized A, diagonal zeroed
  __shared__ float diagl[17];     // diag of A

  const int tid  = threadIdx.x;
  const int lane = tid & 63;
  const int wv   = tid >> 6;
  const int m16  = lane & 15;
  const int qd   = lane >> 4;

  const int phys = blockIdx.x;
  const int xcd  = phys & 7;
  const int iseq = phys >> 3;                // 0..511 within this XCD
  const int bt   = xcd * 256 + (iseq >> 1);  // batch tile: rows bt*68 .. +68
  const int ct   = iseq & 1;                 // col tile (128 d); pair shares x

  for (int idx = tid; idx < 289; idx += 256) {
    int i = idx / 17, j = idx - i * 17;
    float v = 0.5f * ((adj[i*17+j] + adj2[i*17+j]) + (adj[j*17+i] + adj2[j*17+i]));
    aoff[idx] = (i == j) ? 0.0f : v;
    if (i == j) diagl[i] = adj[i*17+i] + adj2[i*17+i];
  }

  // ---- stage x tile: 68 rows x 256 k, fp32 -> bf16 LDS (stride 264 shorts) ----
  {
    const float* xbase = x + (size_t)bt * 68 * 256;
    const int c4 = (tid & 63) << 2;   // col quad: 64 quads = 256 cols = 1 row/wave-op
    const int r0 = tid >> 6;          // 0..3
    #pragma unroll
    for (int it = 0; it < 17; ++it) {
      int row = r0 + it * 4;
      f32x4 v = *(const f32x4*)&xbase[row * 256 + c4];
      *(s16x4*)&smem[row * 264 + c4] = pack4(v);
    }
  }

  f32x4 acc[5][4];  // [rowfrag][mat*2+colfrag]
  #pragma unroll
  for (int a = 0; a < 5; ++a)
    #pragma unroll
    for (int b = 0; b < 4; ++b) acc[a][b] = (f32x4)0.0f;

  const short* wbase = Wt + (ct * 128 + wv * 32 + m16) * 256;  // + mat*65536 + cf*4096

  __syncthreads();   // xs ready

  // A-row indices (clamped: rows 68..79 read row 67; their C-rows are never stored)
  int arow[5];
  #pragma unroll
  for (int rf = 0; rf < 5; ++rf) {
    int r = rf * 16 + m16;
    arow[rf] = (r < 68 ? r : 67) * 264;
  }

  #pragma unroll
  for (int ks = 0; ks < 8; ++ks) {
    const int kq = ks * 32 + qd * 8;
    bf16x8 bfr[4];
    #pragma unroll
    for (int mc = 0; mc < 4; ++mc) {
      int mat = mc >> 1, cf = mc & 1;
      s16x8 t = *(const s16x8*)&wbase[mat * 65536 + cf * 4096 + kq];
      bfr[mc] = __builtin_bit_cast(bf16x8, t);
    }
    #pragma unroll
    for (int rf = 0; rf < 5; ++rf) {
      s16x8 t = *(const s16x8*)&smem[arow[rf] + kq];
      bf16x8 af = __builtin_bit_cast(bf16x8, t);
      #pragma unroll
      for (int mc = 0; mc < 4; ++mc)
        acc[rf][mc] = __builtin_amdgcn_mfma_f32_16x16x32_bf16(af, bfr[mc], acc[rf][mc], 0, 0, 0);
    }
  }

  __syncthreads();   // all waves done reading xs; reuse smem for epilogue
  short* sbuf = smem;          // [68][132] bf16: diag_i*M*h0
  short* gbuf = smem + 8976;   // [68][132] bf16: M*h1

  // phase 1: registers (C-layout: col=lane&15, row=(lane>>4)*4+reg) -> LDS as bf16
  #pragma unroll
  for (int rf = 0; rf < 5; ++rf) {
    #pragma unroll
    for (int cf = 0; cf < 2; ++cf) {
      int c = wv * 32 + cf * 16 + m16;
      #pragma unroll
      for (int reg = 0; reg < 4; ++reg) {
        int r = rf * 16 + qd * 4 + reg;
        if (r < 68) {
          int n = r % 17;
          float mv = M[n * 256 + ct * 128 + c];
          sbuf[r * 132 + c] = f2b(diagl[n] * mv * acc[rf][cf][reg]);
          gbuf[r * 132 + c] = f2b(mv * acc[rf][2 + cf][reg]);
        }
      }
    }
  }
  __syncthreads();
  // phase 2: mixing. i,j uniform across threads -> aoff reads are broadcasts.
  const int d7   = tid & 127;
  const int half = tid >> 7;
  const float bi = bias[ct * 128 + d7];
  for (int gg = 0; gg < 2; ++gg) {
    int g = half * 2 + gg;           // batch-group within tile (0..3)
    int rbase = g * 17;
    float gr[17];
    #pragma unroll
    for (int j = 0; j < 17; ++j) gr[j] = b2f(gbuf[(rbase + j) * 132 + d7]);
    #pragma unroll
    for (int i = 0; i < 17; ++i) {
      float s = b2f(sbuf[(rbase + i) * 132 + d7]) + bi;
      #pragma unroll
      for (int j = 0; j < 17; ++j) s += aoff[i * 17 + j] * gr[j];
      out[((bt * 4 + g) * 17 + i) * 256 + ct * 128 + d7] = s;
    }
  }
}

extern "C" void kernel_launch(void* const* d_in, const int* in_sizes, int n_in,
                              void* d_out, int out_size, void* d_ws, size_t ws_size,
                              hipStream_t stream) {
  const float* x    = (const float*)d_in[0];
  const float* W    = (const float*)d_in[1];
  const float* M    = (const float*)d_in[2];
  const float* adj  = (const float*)d_in[3];
  const float* adj2 = (const float*)d_in[4];
  const float* bias = (const float*)d_in[5];
  float* out = (float*)d_out;
  short* Wt  = (short*)d_ws;   // 262144 B scratch for transposed bf16 weights

  prep_wt<<<128, 256, 0, stream>>>(W, Wt);
  fused_mgc<<<4096, 256, 0, stream>>>(x, Wt, M, adj, adj2, bias, out);
}